// Round 4
// baseline (485.320 us; speedup 1.0000x reference)
//
#include <hip/hip_runtime.h>
#include <stdint.h>

typedef int   i32x8 __attribute__((ext_vector_type(8)));
typedef float f32x4 __attribute__((ext_vector_type(4)));

#define B_ROWS 8192
#define D_DIM  512
#define N_BLOCKS 4096

// monotone float<->uint encoding: enc order == float order (so uint atomicMin
// == float min). f>=0: set sign bit; f<0: bitwise NOT.
__device__ __forceinline__ uint32_t enc_f32(float f) {
  uint32_t s = __float_as_uint(f);
  return (s & 0x80000000u) ? ~s : (s | 0x80000000u);
}
__device__ __forceinline__ float dec_f32(uint32_t e) {
  uint32_t s = (e & 0x80000000u) ? (e ^ 0x80000000u) : ~e;
  return __uint_as_float(s);
}

// ---------------------------------------------------------------------------
// Kernel 1: per-row normalize (fp32 -> fp8 e4m3) + cos(anchor, positive).
// Wave per row. Also inits minenc[r] = +inf encoding and zeroes the
// completion counter (graph-replay safe re-init every run).
// ---------------------------------------------------------------------------
__global__ __launch_bounds__(256) void norm_kernel(
    const float* __restrict__ anchor, const float* __restrict__ positive,
    uint32_t* __restrict__ a8, uint32_t* __restrict__ p8,
    float* __restrict__ cos_ap, uint32_t* __restrict__ minenc,
    uint32_t* __restrict__ donecnt)
{
  const int wave = threadIdx.x >> 6, lane = threadIdx.x & 63;
  const int r = blockIdx.x * 4 + wave;

  if (blockIdx.x == 0 && threadIdx.x == 0) *donecnt = 0u;

  const float4* av = (const float4*)(anchor   + (size_t)r * D_DIM) + lane * 2;
  const float4* pv = (const float4*)(positive + (size_t)r * D_DIM) + lane * 2;
  float4 a0 = av[0], a1 = av[1];
  float4 p0 = pv[0], p1 = pv[1];

  float sa = a0.x*a0.x + a0.y*a0.y + a0.z*a0.z + a0.w*a0.w
           + a1.x*a1.x + a1.y*a1.y + a1.z*a1.z + a1.w*a1.w;
  float sp = p0.x*p0.x + p0.y*p0.y + p0.z*p0.z + p0.w*p0.w
           + p1.x*p1.x + p1.y*p1.y + p1.z*p1.z + p1.w*p1.w;
  float dp = a0.x*p0.x + a0.y*p0.y + a0.z*p0.z + a0.w*p0.w
           + a1.x*p1.x + a1.y*p1.y + a1.z*p1.z + a1.w*p1.w;

#pragma unroll
  for (int d = 1; d < 64; d <<= 1) {
    sa += __shfl_xor(sa, d);
    sp += __shfl_xor(sp, d);
    dp += __shfl_xor(dp, d);
  }

  const float na = sqrtf(sa), np = sqrtf(sp);
  const float ia = 1.0f / na, ip = 1.0f / np;

  float na0 = a0.x*ia, na1 = a0.y*ia, na2 = a0.z*ia, na3 = a0.w*ia;
  float na4 = a1.x*ia, na5 = a1.y*ia, na6 = a1.z*ia, na7 = a1.w*ia;
  float np0 = p0.x*ip, np1 = p0.y*ip, np2 = p0.z*ip, np3 = p0.w*ip;
  float np4 = p1.x*ip, np5 = p1.y*ip, np6 = p1.z*ip, np7 = p1.w*ip;

  uint32_t aw0 = __builtin_amdgcn_cvt_pk_fp8_f32(na0, na1, 0,  false);
  aw0          = __builtin_amdgcn_cvt_pk_fp8_f32(na2, na3, aw0, true);
  uint32_t aw1 = __builtin_amdgcn_cvt_pk_fp8_f32(na4, na5, 0,  false);
  aw1          = __builtin_amdgcn_cvt_pk_fp8_f32(na6, na7, aw1, true);
  uint32_t pw0 = __builtin_amdgcn_cvt_pk_fp8_f32(np0, np1, 0,  false);
  pw0          = __builtin_amdgcn_cvt_pk_fp8_f32(np2, np3, pw0, true);
  uint32_t pw1 = __builtin_amdgcn_cvt_pk_fp8_f32(np4, np5, 0,  false);
  pw1          = __builtin_amdgcn_cvt_pk_fp8_f32(np6, np7, pw1, true);

  ((uint2*)a8)[(size_t)r * 64 + lane] = make_uint2(aw0, aw1);
  ((uint2*)p8)[(size_t)r * 64 + lane] = make_uint2(pw0, pw1);

  if (lane == 0) {
    cos_ap[r] = dp / fmaxf(na * np, 1e-8f);
    minenc[r] = 0xFFFFFFFFu;   // +inf in monotone encoding
  }
}

// ---------------------------------------------------------------------------
// global -> LDS direct load, 16B per lane (dest = wave-uniform base + lane*16).
// ---------------------------------------------------------------------------
__device__ __forceinline__ void load16_to_lds(const void* g, void* l) {
  __builtin_amdgcn_global_load_lds(
      (__attribute__((address_space(1))) uint32_t*)(uintptr_t)(g),
      (__attribute__((address_space(3))) uint32_t*)(uintptr_t)(l),
      16, 0, 0);
}

// ---------------------------------------------------------------------------
// Kernel 2: 128x128 fp8 MX-MFMA tile of sim = A_n * P_n^T (scale=1.0), fused
// diagonal-masked row-min -> device atomicMin on encoded floats, fused
// final loss reduction in the last block to finish.
//
// R4 structure: P staged in LDS (double-buffered, XOR-swizzled, 34 KB) as in
// R0. A fragments come from global (per-XCD-L2-resident slice) with ONE-ITER
// REGISTER LOOKAHEAD: A(k+1) loads issue during iter k (between ds_read and
// MFMA), double-buffered in afA/afB (2x32 regs, parity-selected with
// compile-time ternaries; all-static indexing). The pre-barrier vmcnt(0)
// drain finds them complete (hidden under MFMA(k)).
//   R2 failed: A(k) issued right before barrier(k) -> naked L2 latency/iter.
//   R3 failed: afk[4][4]=128 regs hoisted across 4 barriers -> allocator
//   bailed to scratch (VGPR_Count 116, MfmaUtil 3.4%).
// Per-iter: 8 ds_read_b128 (P) + 4 global_load_lds (P next) + 8 L2 reg-loads
// (A next) + 16 MFMA. VGPR ~185 < 256 cap of __launch_bounds__(256,2).
//
// Block swizzle: xcd = bid&7 owns A-rowTiles [xcd*8, xcd*8+8) for ALL 64
// colTiles (A stays L2-resident: 512 KB/XCD; P streams once: 4 MB/XCD).
// ---------------------------------------------------------------------------
__global__ __launch_bounds__(256, 2) void simmin_kernel(
    const uint8_t* __restrict__ a8, const uint8_t* __restrict__ p8,
    uint32_t* __restrict__ minenc, const float* __restrict__ cos_ap,
    uint32_t* __restrict__ donecnt, float* __restrict__ out)
{
  __shared__ __attribute__((aligned(16))) uint8_t Plds[2][128 * 128];
  __shared__ float redmin[256];

  const int tid  = threadIdx.x;
  const int lane = tid & 63;
  const int wave = tid >> 6;
  const int waveM = wave >> 1, waveN = wave & 1;
  const int quad = lane >> 4;
  const int l15  = lane & 15;

  // super-tile swizzle (see header comment)
  const int bid = blockIdx.x;
  const int blockRow = (bid & 7) * 8 + ((bid >> 3) & 7);
  const int blockCol = bid >> 6;

  f32x4 acc[4][4];
  const f32x4 zero = {0.f, 0.f, 0.f, 0.f};
#pragma unroll
  for (int i = 0; i < 4; i++)
#pragma unroll
    for (int j = 0; j < 4; j++) acc[i][j] = zero;

  // P staging: chunk = 8 rows x 128B; lane i: row = i/8, XOR-swizzled k-slot
  // fetched pre-swizzled on the global side (LDS side must stay contiguous).
  const int srow = lane >> 3;
  const int sk   = (lane & 7) ^ srow;
  const uint8_t* pBase = p8 + (size_t)(blockCol * 128) * D_DIM;

  auto stage = [&](int k0, int buf) {
#pragma unroll
    for (int c = 0; c < 4; c++) {
      const int chunk = wave * 4 + c;       // 0..15
      const size_t goff = (size_t)(chunk * 8 + srow) * D_DIM + k0 + sk * 16;
      load16_to_lds(pBase + goff, &Plds[buf][chunk * 1024]);
    }
  };

  // A fragment addressing (verified R2/R3, absmax 0.0): lane covers row
  // (blockRow*128 + waveM*64 + mf*16 + l15), bytes [k*128 + quad*32, +32).
  const uint8_t* aFragBase =
      a8 + (size_t)(blockRow * 128 + waveM * 64 + l15) * D_DIM + quad * 32;

#define LOAD_AF(dst, kk)                                                      \
  {                                                                           \
    _Pragma("unroll")                                                         \
    for (int mf = 0; mf < 4; mf++) {                                          \
      const uint8_t* ap = aFragBase + (size_t)(mf * 16) * D_DIM + (kk) * 128; \
      const int4 lo = *(const int4*)(ap);                                     \
      const int4 hi = *(const int4*)(ap + 16);                                \
      dst[mf] = (i32x8){lo.x, lo.y, lo.z, lo.w, hi.x, hi.y, hi.z, hi.w};      \
    }                                                                         \
  }

  i32x8 afA[4], afB[4];
  LOAD_AF(afA, 0);        // A(0): latency hidden under stage(0) + barrier
  stage(0, 0);

#pragma unroll
  for (int k = 0; k < 4; k++) {
    const int buf = k & 1;

    __syncthreads();  // P tile k in LDS; A(k) regs complete (drained pre-barrier)

    i32x8 bfr[4];
#pragma unroll
    for (int nf = 0; nf < 4; nf++) {
      const int r = waveN * 64 + nf * 16 + l15;
      const int rx = r & 7;
      const int4 lo = *(const int4*)&Plds[buf][r * 128 + (((quad * 2 + 0) ^ rx) * 16)];
      const int4 hi = *(const int4*)&Plds[buf][r * 128 + (((quad * 2 + 1) ^ rx) * 16)];
      bfr[nf] = (i32x8){lo.x, lo.y, lo.z, lo.w, hi.x, hi.y, hi.z, hi.w};
    }

    // prefetch NEXT tile: P -> LDS (other buffer), A -> other reg buffer.
    // Issued before the MFMA block so their latency hides under it.
    if (k < 3) {
      stage((k + 1) * 128, buf ^ 1);
      if ((k & 1) == 0) { LOAD_AF(afB, k + 1); }
      else              { LOAD_AF(afA, k + 1); }
    }

#pragma unroll
    for (int mf = 0; mf < 4; mf++)
#pragma unroll
      for (int nf = 0; nf < 4; nf++)
        acc[mf][nf] = __builtin_amdgcn_mfma_scale_f32_16x16x128_f8f6f4(
            (k & 1) ? afB[mf] : afA[mf], bfr[nf], acc[mf][nf],
            0, 0,                 // cbsz=fp8(e4m3) A, blgp=fp8(e4m3) B
            0, 0x7F7F7F7F,        // scale A (2^0)
            0, 0x7F7F7F7F);       // scale B (2^0)
  }
#undef LOAD_AF

  // ---- fused epilogue: per-row min over this block's 128 cols, diag masked
  const int rowTileBase = blockRow * 128 + waveM * 64;
  const int colTileBase = blockCol * 128 + waveN * 64;

  float rm[4][4];
#pragma unroll
  for (int mf = 0; mf < 4; mf++)
#pragma unroll
    for (int r = 0; r < 4; r++) rm[mf][r] = 3.0e38f;

#pragma unroll
  for (int mf = 0; mf < 4; mf++) {
#pragma unroll
    for (int nf = 0; nf < 4; nf++) {
      const int col = colTileBase + nf * 16 + l15;
#pragma unroll
      for (int r = 0; r < 4; r++) {
        const int row = rowTileBase + mf * 16 + quad * 4 + r;
        const float v = acc[mf][nf][r];
        rm[mf][r] = (row == col) ? rm[mf][r] : fminf(rm[mf][r], v);
      }
    }
  }
#pragma unroll
  for (int d = 1; d < 16; d <<= 1)
#pragma unroll
    for (int mf = 0; mf < 4; mf++)
#pragma unroll
      for (int r = 0; r < 4; r++)
        rm[mf][r] = fminf(rm[mf][r], __shfl_xor(rm[mf][r], d));

  if (l15 == 0) {
#pragma unroll
    for (int mf = 0; mf < 4; mf++)
#pragma unroll
      for (int r = 0; r < 4; r++)
        redmin[waveN * 128 + waveM * 64 + mf * 16 + quad * 4 + r] = rm[mf][r];
  }
  __syncthreads();

  if (tid < 128) {
    const float m = fminf(redmin[tid], redmin[128 + tid]);
    atomicMin(&minenc[blockRow * 128 + tid], enc_f32(m));  // device-scope
  }

  // ---- fused finalize: last block to finish computes the loss mean.
  __threadfence();   // device-scope release of our atomicMins
  __syncthreads();   // all lanes' mins + fences done before the count
  __shared__ int lastFlag;
  if (tid == 0) {
    uint32_t prev = __hip_atomic_fetch_add(donecnt, 1u, __ATOMIC_ACQ_REL,
                                           __HIP_MEMORY_SCOPE_AGENT);
    lastFlag = (prev == N_BLOCKS - 1);
  }
  __syncthreads();
  if (!lastFlag) return;

  // 256 threads, 32 rows each. minenc via agent-scope atomic loads (bypass
  // L1, coherent vs other XCDs' atomicMins). cos_ap written by the previous
  // dispatch (boundary maintenance makes it visible to plain loads).
  float sum = 0.0f;
#pragma unroll
  for (int i = 0; i < B_ROWS / 256; i++) {
    const int r = i * 256 + tid;
    const uint32_t e = __hip_atomic_load(&minenc[r], __ATOMIC_RELAXED,
                                         __HIP_MEMORY_SCOPE_AGENT);
    sum += fmaxf(0.0f, 1.0f + cos_ap[r] - dec_f32(e));
  }
#pragma unroll
  for (int d = 1; d < 64; d <<= 1) sum += __shfl_xor(sum, d);
  if (lane == 0) redmin[wave] = sum;   // reuse redmin LDS
  __syncthreads();
  if (tid == 0) {
    const float t = redmin[0] + redmin[1] + redmin[2] + redmin[3];
    out[0] = t * (1.0f / (float)B_ROWS);
  }
}

// ---------------------------------------------------------------------------
extern "C" void kernel_launch(void* const* d_in, const int* in_sizes, int n_in,
                              void* d_out, int out_size, void* d_ws, size_t ws_size,
                              hipStream_t stream) {
  const float* anchor   = (const float*)d_in[0];
  const float* positive = (const float*)d_in[1];

  char* ws = (char*)d_ws;
  uint32_t* a8      = (uint32_t*)(ws);                                // 4 MB
  uint32_t* p8      = (uint32_t*)(ws + (4ull << 20));                 // 4 MB
  float*    cos_ap  = (float*)(ws + (8ull << 20));                    // 32 KB
  uint32_t* minenc  = (uint32_t*)(ws + (8ull << 20) + (32ull << 10)); // 32 KB
  uint32_t* donecnt = (uint32_t*)(ws + (8ull << 20) + (64ull << 10)); // 4 B
  float*    out = (float*)d_out;

  norm_kernel<<<B_ROWS / 4, 256, 0, stream>>>(anchor, positive, a8, p8,
                                              cos_ap, minenc, donecnt);
  simmin_kernel<<<N_BLOCKS, 256, 0, stream>>>((const uint8_t*)a8,
                                              (const uint8_t*)p8, minenc,
                                              cos_ap, donecnt, out);
}

// Round 5
// 145.606 us; speedup vs baseline: 3.3331x; 3.3331x over previous
//
#include <hip/hip_runtime.h>
#include <stdint.h>

typedef int   i32x8 __attribute__((ext_vector_type(8)));
typedef float f32x4 __attribute__((ext_vector_type(4)));

#define B_ROWS 8192
#define D_DIM  512
#define N_BLOCKS 4096

// monotone float<->uint encoding: enc order == float order (so uint atomicMin
// == float min). f>=0: set sign bit; f<0: bitwise NOT.
__device__ __forceinline__ uint32_t enc_f32(float f) {
  uint32_t s = __float_as_uint(f);
  return (s & 0x80000000u) ? ~s : (s | 0x80000000u);
}
__device__ __forceinline__ float dec_f32(uint32_t e) {
  uint32_t s = (e & 0x80000000u) ? (e ^ 0x80000000u) : ~e;
  return __uint_as_float(s);
}

// ---------------------------------------------------------------------------
// Kernel 1: per-row normalize (fp32 -> fp8 e4m3) + cos(anchor, positive).
// Wave per row. Also inits minenc[r] = +inf encoding (replaces a memset node).
// ---------------------------------------------------------------------------
__global__ __launch_bounds__(256) void norm_kernel(
    const float* __restrict__ anchor, const float* __restrict__ positive,
    uint32_t* __restrict__ a8, uint32_t* __restrict__ p8,
    float* __restrict__ cos_ap, uint32_t* __restrict__ minenc)
{
  const int wave = threadIdx.x >> 6, lane = threadIdx.x & 63;
  const int r = blockIdx.x * 4 + wave;

  const float4* av = (const float4*)(anchor   + (size_t)r * D_DIM) + lane * 2;
  const float4* pv = (const float4*)(positive + (size_t)r * D_DIM) + lane * 2;
  float4 a0 = av[0], a1 = av[1];
  float4 p0 = pv[0], p1 = pv[1];

  float sa = a0.x*a0.x + a0.y*a0.y + a0.z*a0.z + a0.w*a0.w
           + a1.x*a1.x + a1.y*a1.y + a1.z*a1.z + a1.w*a1.w;
  float sp = p0.x*p0.x + p0.y*p0.y + p0.z*p0.z + p0.w*p0.w
           + p1.x*p1.x + p1.y*p1.y + p1.z*p1.z + p1.w*p1.w;
  float dp = a0.x*p0.x + a0.y*p0.y + a0.z*p0.z + a0.w*p0.w
           + a1.x*p1.x + a1.y*p1.y + a1.z*p1.z + a1.w*p1.w;

#pragma unroll
  for (int d = 1; d < 64; d <<= 1) {
    sa += __shfl_xor(sa, d);
    sp += __shfl_xor(sp, d);
    dp += __shfl_xor(dp, d);
  }

  const float na = sqrtf(sa), np = sqrtf(sp);
  const float ia = 1.0f / na, ip = 1.0f / np;

  float na0 = a0.x*ia, na1 = a0.y*ia, na2 = a0.z*ia, na3 = a0.w*ia;
  float na4 = a1.x*ia, na5 = a1.y*ia, na6 = a1.z*ia, na7 = a1.w*ia;
  float np0 = p0.x*ip, np1 = p0.y*ip, np2 = p0.z*ip, np3 = p0.w*ip;
  float np4 = p1.x*ip, np5 = p1.y*ip, np6 = p1.z*ip, np7 = p1.w*ip;

  uint32_t aw0 = __builtin_amdgcn_cvt_pk_fp8_f32(na0, na1, 0,  false);
  aw0          = __builtin_amdgcn_cvt_pk_fp8_f32(na2, na3, aw0, true);
  uint32_t aw1 = __builtin_amdgcn_cvt_pk_fp8_f32(na4, na5, 0,  false);
  aw1          = __builtin_amdgcn_cvt_pk_fp8_f32(na6, na7, aw1, true);
  uint32_t pw0 = __builtin_amdgcn_cvt_pk_fp8_f32(np0, np1, 0,  false);
  pw0          = __builtin_amdgcn_cvt_pk_fp8_f32(np2, np3, pw0, true);
  uint32_t pw1 = __builtin_amdgcn_cvt_pk_fp8_f32(np4, np5, 0,  false);
  pw1          = __builtin_amdgcn_cvt_pk_fp8_f32(np6, np7, pw1, true);

  ((uint2*)a8)[(size_t)r * 64 + lane] = make_uint2(aw0, aw1);
  ((uint2*)p8)[(size_t)r * 64 + lane] = make_uint2(pw0, pw1);

  if (lane == 0) {
    cos_ap[r] = dp / fmaxf(na * np, 1e-8f);
    minenc[r] = 0xFFFFFFFFu;   // +inf in monotone encoding
  }
}

// ---------------------------------------------------------------------------
// global -> LDS direct load, 16B per lane (dest = wave-uniform base + lane*16).
// ---------------------------------------------------------------------------
__device__ __forceinline__ void load16_to_lds(const void* g, void* l) {
  __builtin_amdgcn_global_load_lds(
      (__attribute__((address_space(1))) uint32_t*)(uintptr_t)(g),
      (__attribute__((address_space(3))) uint32_t*)(uintptr_t)(l),
      16, 0, 0);
}

// ---------------------------------------------------------------------------
// Kernel 2: 128x128 fp8 MX-MFMA tile of sim = A_n * P_n^T (scale=1.0), fused
// diagonal-masked row-min -> device atomicMin on encoded floats.
//
// K-loop (R4 structure, first clean measurement this round): P staged in LDS
// (double-buffered, XOR-swizzled, 34 KB). A fragments from global (per-XCD-
// L2-resident slice) with ONE-ITER REGISTER LOOKAHEAD: A(k+1) issues during
// iter k BEFORE the MFMA block (so ~1100cy of MFMA covers the L2 latency;
// the pre-barrier vmcnt(0) drain finds them complete). afA/afB parity
// buffers, compile-time-selected -> static indexing only.
//   R2 lesson: A(k) issued right before barrier(k) -> naked L2 latency/iter.
//   R3/R4 lesson: the ~340us regression was the fused-finalize per-block
//   __threadfence (agent-scope L2 writeback/inv x4096 blocks) + single-addr
//   ACQ_REL RMW -- NOT the K-loop. Finalize is a separate kernel again;
//   kernel-boundary coherence is free and verified (R0-R2).
// Per-iter: 8 ds_read_b128 (P) + 4 global_load_lds (P next) + 8 L2 reg-loads
// (A next) + 16 MFMA.
//
// Block swizzle: xcd = bid&7 owns A-rowTiles [xcd*8, xcd*8+8) for ALL 64
// colTiles (A stays L2-resident: 512 KB/XCD; P streams once: 4 MB/XCD).
// ---------------------------------------------------------------------------
__global__ __launch_bounds__(256, 2) void simmin_kernel(
    const uint8_t* __restrict__ a8, const uint8_t* __restrict__ p8,
    uint32_t* __restrict__ minenc)
{
  __shared__ __attribute__((aligned(16))) uint8_t Plds[2][128 * 128];
  __shared__ float redmin[256];

  const int tid  = threadIdx.x;
  const int lane = tid & 63;
  const int wave = tid >> 6;
  const int waveM = wave >> 1, waveN = wave & 1;
  const int quad = lane >> 4;
  const int l15  = lane & 15;

  // super-tile swizzle (see header comment)
  const int bid = blockIdx.x;
  const int blockRow = (bid & 7) * 8 + ((bid >> 3) & 7);
  const int blockCol = bid >> 6;

  f32x4 acc[4][4];
  const f32x4 zero = {0.f, 0.f, 0.f, 0.f};
#pragma unroll
  for (int i = 0; i < 4; i++)
#pragma unroll
    for (int j = 0; j < 4; j++) acc[i][j] = zero;

  // P staging: chunk = 8 rows x 128B; lane i: row = i/8, XOR-swizzled k-slot
  // fetched pre-swizzled on the global side (LDS side must stay contiguous).
  const int srow = lane >> 3;
  const int sk   = (lane & 7) ^ srow;
  const uint8_t* pBase = p8 + (size_t)(blockCol * 128) * D_DIM;

  auto stage = [&](int k0, int buf) {
#pragma unroll
    for (int c = 0; c < 4; c++) {
      const int chunk = wave * 4 + c;       // 0..15
      const size_t goff = (size_t)(chunk * 8 + srow) * D_DIM + k0 + sk * 16;
      load16_to_lds(pBase + goff, &Plds[buf][chunk * 1024]);
    }
  };

  // A fragment addressing (verified R2-R4, absmax 0.0): lane covers row
  // (blockRow*128 + waveM*64 + mf*16 + l15), bytes [k*128 + quad*32, +32).
  const uint8_t* aFragBase =
      a8 + (size_t)(blockRow * 128 + waveM * 64 + l15) * D_DIM + quad * 32;

#define LOAD_AF(dst, kk)                                                      \
  {                                                                           \
    _Pragma("unroll")                                                         \
    for (int mf = 0; mf < 4; mf++) {                                          \
      const uint8_t* ap = aFragBase + (size_t)(mf * 16) * D_DIM + (kk) * 128; \
      const int4 lo = *(const int4*)(ap);                                     \
      const int4 hi = *(const int4*)(ap + 16);                                \
      dst[mf] = (i32x8){lo.x, lo.y, lo.z, lo.w, hi.x, hi.y, hi.z, hi.w};      \
    }                                                                         \
  }

  i32x8 afA[4], afB[4];
  LOAD_AF(afA, 0);        // A(0): latency hidden under stage(0) + barrier
  stage(0, 0);

#pragma unroll
  for (int k = 0; k < 4; k++) {
    const int buf = k & 1;

    __syncthreads();  // P tile k in LDS; A(k) regs complete (drained pre-barrier)

    i32x8 bfr[4];
#pragma unroll
    for (int nf = 0; nf < 4; nf++) {
      const int r = waveN * 64 + nf * 16 + l15;
      const int rx = r & 7;
      const int4 lo = *(const int4*)&Plds[buf][r * 128 + (((quad * 2 + 0) ^ rx) * 16)];
      const int4 hi = *(const int4*)&Plds[buf][r * 128 + (((quad * 2 + 1) ^ rx) * 16)];
      bfr[nf] = (i32x8){lo.x, lo.y, lo.z, lo.w, hi.x, hi.y, hi.z, hi.w};
    }

    // prefetch NEXT tile: P -> LDS (other buffer), A -> other reg buffer.
    // Issued before the MFMA block so their latency hides under it.
    if (k < 3) {
      stage((k + 1) * 128, buf ^ 1);
      if ((k & 1) == 0) { LOAD_AF(afB, k + 1); }
      else              { LOAD_AF(afA, k + 1); }
    }

#pragma unroll
    for (int mf = 0; mf < 4; mf++)
#pragma unroll
      for (int nf = 0; nf < 4; nf++)
        acc[mf][nf] = __builtin_amdgcn_mfma_scale_f32_16x16x128_f8f6f4(
            (k & 1) ? afB[mf] : afA[mf], bfr[nf], acc[mf][nf],
            0, 0,                 // cbsz=fp8(e4m3) A, blgp=fp8(e4m3) B
            0, 0x7F7F7F7F,        // scale A (2^0)
            0, 0x7F7F7F7F);       // scale B (2^0)
  }
#undef LOAD_AF

  // ---- fused epilogue: per-row min over this block's 128 cols, diag masked
  const int rowTileBase = blockRow * 128 + waveM * 64;
  const int colTileBase = blockCol * 128 + waveN * 64;

  float rm[4][4];
#pragma unroll
  for (int mf = 0; mf < 4; mf++)
#pragma unroll
    for (int r = 0; r < 4; r++) rm[mf][r] = 3.0e38f;

#pragma unroll
  for (int mf = 0; mf < 4; mf++) {
#pragma unroll
    for (int nf = 0; nf < 4; nf++) {
      const int col = colTileBase + nf * 16 + l15;
#pragma unroll
      for (int r = 0; r < 4; r++) {
        const int row = rowTileBase + mf * 16 + quad * 4 + r;
        const float v = acc[mf][nf][r];
        rm[mf][r] = (row == col) ? rm[mf][r] : fminf(rm[mf][r], v);
      }
    }
  }
#pragma unroll
  for (int d = 1; d < 16; d <<= 1)
#pragma unroll
    for (int mf = 0; mf < 4; mf++)
#pragma unroll
      for (int r = 0; r < 4; r++)
        rm[mf][r] = fminf(rm[mf][r], __shfl_xor(rm[mf][r], d));

  if (l15 == 0) {
#pragma unroll
    for (int mf = 0; mf < 4; mf++)
#pragma unroll
      for (int r = 0; r < 4; r++)
        redmin[waveN * 128 + waveM * 64 + mf * 16 + quad * 4 + r] = rm[mf][r];
  }
  __syncthreads();

  if (tid < 128) {
    const float m = fminf(redmin[tid], redmin[128 + tid]);
    atomicMin(&minenc[blockRow * 128 + tid], enc_f32(m));  // device-scope
  }
}

// ---------------------------------------------------------------------------
// Kernel 3: single block (1024 thr) — decode row-mins, loss, mean, store.
// Separate launch: kernel-boundary coherence makes plain loads correct
// (verified R0-R2); per-block device fences inside simmin cost ~340us (R3/R4).
// ---------------------------------------------------------------------------
__global__ __launch_bounds__(1024) void finalize_kernel(
    const uint32_t* __restrict__ minenc, const float* __restrict__ cos_ap,
    float* __restrict__ out)
{
  float sum = 0.0f;
#pragma unroll
  for (int r = threadIdx.x; r < B_ROWS; r += 1024)
    sum += fmaxf(0.0f, 1.0f + cos_ap[r] - dec_f32(minenc[r]));

#pragma unroll
  for (int d = 1; d < 64; d <<= 1) sum += __shfl_xor(sum, d);
  __shared__ float s[16];
  if ((threadIdx.x & 63) == 0) s[threadIdx.x >> 6] = sum;
  __syncthreads();
  if (threadIdx.x < 64) {
    float t = (threadIdx.x < 16) ? s[threadIdx.x] : 0.0f;
#pragma unroll
    for (int d = 1; d < 16; d <<= 1) t += __shfl_xor(t, d);
    if (threadIdx.x == 0) out[0] = t * (1.0f / (float)B_ROWS);
  }
}

// ---------------------------------------------------------------------------
extern "C" void kernel_launch(void* const* d_in, const int* in_sizes, int n_in,
                              void* d_out, int out_size, void* d_ws, size_t ws_size,
                              hipStream_t stream) {
  const float* anchor   = (const float*)d_in[0];
  const float* positive = (const float*)d_in[1];

  char* ws = (char*)d_ws;
  uint32_t* a8     = (uint32_t*)(ws);                                // 4 MB
  uint32_t* p8     = (uint32_t*)(ws + (4ull << 20));                 // 4 MB
  float*    cos_ap = (float*)(ws + (8ull << 20));                    // 32 KB
  uint32_t* minenc = (uint32_t*)(ws + (8ull << 20) + (32ull << 10)); // 32 KB
  float*    out = (float*)d_out;

  norm_kernel<<<B_ROWS / 4, 256, 0, stream>>>(anchor, positive, a8, p8,
                                              cos_ap, minenc);
  simmin_kernel<<<N_BLOCKS, 256, 0, stream>>>((const uint8_t*)a8,
                                              (const uint8_t*)p8, minenc);
  finalize_kernel<<<1, 1024, 0, stream>>>(minenc, cos_ap, out);
}

// Round 6
// 125.853 us; speedup vs baseline: 3.8562x; 1.1570x over previous
//
#include <hip/hip_runtime.h>
#include <stdint.h>

typedef int   i32x8 __attribute__((ext_vector_type(8)));
typedef float f32x4 __attribute__((ext_vector_type(4)));

#define B_ROWS 8192
#define D_DIM  512
#define BM 256
#define BN 256
#define BK 128
#define N_BLOCKS 1024   // (8192/256)^2

// monotone float<->uint encoding: enc order == float order (so uint atomicMin
// == float min). f>=0: set sign bit; f<0: bitwise NOT.
__device__ __forceinline__ uint32_t enc_f32(float f) {
  uint32_t s = __float_as_uint(f);
  return (s & 0x80000000u) ? ~s : (s | 0x80000000u);
}
__device__ __forceinline__ float dec_f32(uint32_t e) {
  uint32_t s = (e & 0x80000000u) ? (e ^ 0x80000000u) : ~e;
  return __uint_as_float(s);
}

// ---------------------------------------------------------------------------
// Kernel 1: per-row normalize (fp32 -> fp8 e4m3) + cos(anchor, positive).
// Wave per row. Also inits minenc[r] = +inf encoding (replaces a memset node).
// ---------------------------------------------------------------------------
__global__ __launch_bounds__(256) void norm_kernel(
    const float* __restrict__ anchor, const float* __restrict__ positive,
    uint32_t* __restrict__ a8, uint32_t* __restrict__ p8,
    float* __restrict__ cos_ap, uint32_t* __restrict__ minenc)
{
  const int wave = threadIdx.x >> 6, lane = threadIdx.x & 63;
  const int r = blockIdx.x * 4 + wave;

  const float4* av = (const float4*)(anchor   + (size_t)r * D_DIM) + lane * 2;
  const float4* pv = (const float4*)(positive + (size_t)r * D_DIM) + lane * 2;
  float4 a0 = av[0], a1 = av[1];
  float4 p0 = pv[0], p1 = pv[1];

  float sa = a0.x*a0.x + a0.y*a0.y + a0.z*a0.z + a0.w*a0.w
           + a1.x*a1.x + a1.y*a1.y + a1.z*a1.z + a1.w*a1.w;
  float sp = p0.x*p0.x + p0.y*p0.y + p0.z*p0.z + p0.w*p0.w
           + p1.x*p1.x + p1.y*p1.y + p1.z*p1.z + p1.w*p1.w;
  float dp = a0.x*p0.x + a0.y*p0.y + a0.z*p0.z + a0.w*p0.w
           + a1.x*p1.x + a1.y*p1.y + a1.z*p1.z + a1.w*p1.w;

#pragma unroll
  for (int d = 1; d < 64; d <<= 1) {
    sa += __shfl_xor(sa, d);
    sp += __shfl_xor(sp, d);
    dp += __shfl_xor(dp, d);
  }

  const float na = sqrtf(sa), np = sqrtf(sp);
  const float ia = 1.0f / na, ip = 1.0f / np;

  float na0 = a0.x*ia, na1 = a0.y*ia, na2 = a0.z*ia, na3 = a0.w*ia;
  float na4 = a1.x*ia, na5 = a1.y*ia, na6 = a1.z*ia, na7 = a1.w*ia;
  float np0 = p0.x*ip, np1 = p0.y*ip, np2 = p0.z*ip, np3 = p0.w*ip;
  float np4 = p1.x*ip, np5 = p1.y*ip, np6 = p1.z*ip, np7 = p1.w*ip;

  uint32_t aw0 = __builtin_amdgcn_cvt_pk_fp8_f32(na0, na1, 0,  false);
  aw0          = __builtin_amdgcn_cvt_pk_fp8_f32(na2, na3, aw0, true);
  uint32_t aw1 = __builtin_amdgcn_cvt_pk_fp8_f32(na4, na5, 0,  false);
  aw1          = __builtin_amdgcn_cvt_pk_fp8_f32(na6, na7, aw1, true);
  uint32_t pw0 = __builtin_amdgcn_cvt_pk_fp8_f32(np0, np1, 0,  false);
  pw0          = __builtin_amdgcn_cvt_pk_fp8_f32(np2, np3, pw0, true);
  uint32_t pw1 = __builtin_amdgcn_cvt_pk_fp8_f32(np4, np5, 0,  false);
  pw1          = __builtin_amdgcn_cvt_pk_fp8_f32(np6, np7, pw1, true);

  ((uint2*)a8)[(size_t)r * 64 + lane] = make_uint2(aw0, aw1);
  ((uint2*)p8)[(size_t)r * 64 + lane] = make_uint2(pw0, pw1);

  if (lane == 0) {
    cos_ap[r] = dp / fmaxf(na * np, 1e-8f);
    minenc[r] = 0xFFFFFFFFu;   // +inf in monotone encoding
  }
}

// ---------------------------------------------------------------------------
// global -> LDS direct load, 16B per lane (dest = wave-uniform base + lane*16).
// ---------------------------------------------------------------------------
__device__ __forceinline__ void load16_to_lds(const void* g, void* l) {
  __builtin_amdgcn_global_load_lds(
      (__attribute__((address_space(1))) uint32_t*)(uintptr_t)(g),
      (__attribute__((address_space(3))) uint32_t*)(uintptr_t)(l),
      16, 0, 0);
}

// ---------------------------------------------------------------------------
// Kernel 2: 256x256 fp8 MX-MFMA tile of sim = A_n * P_n^T (scale=1.0), fused
// diagonal-masked row-min -> device atomicMin on encoded floats.
//
// R6: tile 128x128 -> 256x256, 8 waves (2M x 4N), 512 thr, BK=128.
// Why: at 128^2 LDS traffic/iter (reads 64KB + stage 32KB ~ 750cy) exceeded
// the block's MFMA work -> LDS-bound at MfmaUtil 22% (R0=62us). At 256^2 the
// arithmetic intensity doubles: MFMA 2200cy/CU-iter vs LDS 256KB ~ 2000cy.
// Settled by R2/R4/R5: A must be LDS-staged (A-from-global is a 512B-stride
// 64-line gather, ~4x MFMA time); fences inside simmin forbidden (R3/R4,
// -340us). All swizzle/fragment/epilogue math identical to verified R0,
// constants scaled. LDS 132KB -> 1 block/CU, 2 waves/SIMD (HK's 256^2 point).
// __launch_bounds__(512,2): VGPR cap 256 for ~210 working set
// (acc 128 + bfr 32 + af 8-16 transient + addressing).
//
// Block swizzle: xcd = bid&7 owns A-rowTiles [xcd*4, xcd*4+4) for ALL 32
// colTiles (A slice 512 KB/XCD stays L2-resident; P streams 4 MB/XCD).
// ---------------------------------------------------------------------------
__global__ __launch_bounds__(512, 2) void simmin_kernel(
    const uint8_t* __restrict__ a8, const uint8_t* __restrict__ p8,
    uint32_t* __restrict__ minenc)
{
  __shared__ __attribute__((aligned(16))) uint8_t Alds[2][BM * BK];
  __shared__ __attribute__((aligned(16))) uint8_t Plds[2][BN * BK];
  __shared__ float redmin[2][4][128];

  const int tid  = threadIdx.x;
  const int lane = tid & 63;
  const int wave = tid >> 6;          // 0..7
  const int waveM = wave >> 2;        // 0..1 (row half)
  const int waveN = wave & 3;         // 0..3 (col quarter)
  const int quad = lane >> 4;
  const int l15  = lane & 15;

  // super-tile swizzle (see header comment): bijective over 1024 blocks
  const int bid = blockIdx.x;
  const int blockRow = (bid & 7) * 4 + ((bid >> 3) & 3);  // 0..31
  const int blockCol = bid >> 5;                          // 0..31

  f32x4 acc[8][4];
  const f32x4 zero = {0.f, 0.f, 0.f, 0.f};
#pragma unroll
  for (int i = 0; i < 8; i++)
#pragma unroll
    for (int j = 0; j < 4; j++) acc[i][j] = zero;

  // staging: chunk = 8 rows x 128B; lane i: row = i/8, XOR-swizzled k-slot
  // fetched pre-swizzled on the global side (LDS side must stay contiguous).
  const int srow = lane >> 3;
  const int sk   = (lane & 7) ^ srow;
  const uint8_t* aBase = a8 + (size_t)(blockRow * BM) * D_DIM;
  const uint8_t* pBase = p8 + (size_t)(blockCol * BN) * D_DIM;

  auto stage = [&](int k0, int buf) {
#pragma unroll
    for (int c = 0; c < 4; c++) {
      const int chunk = wave * 4 + c;       // 0..31 (256 rows / 8 per chunk)
      const size_t goff = (size_t)(chunk * 8 + srow) * D_DIM + k0 + sk * 16;
      load16_to_lds(aBase + goff, &Alds[buf][chunk * 1024]);
      load16_to_lds(pBase + goff, &Plds[buf][chunk * 1024]);
    }
  };

  stage(0, 0);

#pragma unroll
  for (int k = 0; k < 4; k++) {
    const int buf = k & 1;
    __syncthreads();  // drains stage->buf[k]; fences reads of buf from k-2

    // B fragments for this wave's 64 cols (rows of P): read once per iter.
    i32x8 bfr[4];
#pragma unroll
    for (int nf = 0; nf < 4; nf++) {
      const int r = waveN * 64 + nf * 16 + l15;
      const int rx = r & 7;
      const int4 lo = *(const int4*)&Plds[buf][r * BK + (((quad * 2 + 0) ^ rx) * 16)];
      const int4 hi = *(const int4*)&Plds[buf][r * BK + (((quad * 2 + 1) ^ rx) * 16)];
      bfr[nf] = (i32x8){lo.x, lo.y, lo.z, lo.w, hi.x, hi.y, hi.z, hi.w};
    }

    if (k < 3) stage((k + 1) * BK, buf ^ 1);  // prefetch next tile

    // A fragments per mf (8 row-frags of 16); af transient -> low pressure.
#pragma unroll
    for (int mf = 0; mf < 8; mf++) {
      const int r = waveM * 128 + mf * 16 + l15;
      const int rx = r & 7;
      const int4 lo = *(const int4*)&Alds[buf][r * BK + (((quad * 2 + 0) ^ rx) * 16)];
      const int4 hi = *(const int4*)&Alds[buf][r * BK + (((quad * 2 + 1) ^ rx) * 16)];
      const i32x8 af = (i32x8){lo.x, lo.y, lo.z, lo.w, hi.x, hi.y, hi.z, hi.w};
#pragma unroll
      for (int nf = 0; nf < 4; nf++)
        acc[mf][nf] = __builtin_amdgcn_mfma_scale_f32_16x16x128_f8f6f4(
            af, bfr[nf], acc[mf][nf],
            0, 0,                 // cbsz=fp8(e4m3) A, blgp=fp8(e4m3) B
            0, 0x7F7F7F7F,        // scale A (2^0)
            0, 0x7F7F7F7F);       // scale B (2^0)
    }
  }

  // ---- fused epilogue: per-row min over this block's 256 cols, diag masked
  const int rowTileBase = blockRow * BM + waveM * 128;
  const int colTileBase = blockCol * BN + waveN * 64;

  float rm[8][4];
#pragma unroll
  for (int mf = 0; mf < 8; mf++)
#pragma unroll
    for (int r = 0; r < 4; r++) rm[mf][r] = 3.0e38f;

#pragma unroll
  for (int mf = 0; mf < 8; mf++) {
#pragma unroll
    for (int nf = 0; nf < 4; nf++) {
      const int col = colTileBase + nf * 16 + l15;
#pragma unroll
      for (int r = 0; r < 4; r++) {
        const int row = rowTileBase + mf * 16 + quad * 4 + r;
        const float v = acc[mf][nf][r];
        rm[mf][r] = (row == col) ? rm[mf][r] : fminf(rm[mf][r], v);
      }
    }
  }
  // fold across the 16 lanes of each l15-group (cols congruent mod 16)
#pragma unroll
  for (int d = 1; d < 16; d <<= 1)
#pragma unroll
    for (int mf = 0; mf < 8; mf++)
#pragma unroll
      for (int r = 0; r < 4; r++)
        rm[mf][r] = fminf(rm[mf][r], __shfl_xor(rm[mf][r], d));

  // each wave: 128 row-mins over its 64 cols -> LDS slice [waveM][waveN]
  if (l15 == 0) {
#pragma unroll
    for (int mf = 0; mf < 8; mf++)
#pragma unroll
      for (int r = 0; r < 4; r++)
        redmin[waveM][waveN][mf * 16 + quad * 4 + r] = rm[mf][r];
  }
  __syncthreads();

  // fold 4 waveN slices; tid = waveM_r*128 + local row
  if (tid < 256) {
    const int wm = tid >> 7, idx = tid & 127;
    const float m = fminf(fminf(redmin[wm][0][idx], redmin[wm][1][idx]),
                          fminf(redmin[wm][2][idx], redmin[wm][3][idx]));
    atomicMin(&minenc[blockRow * BM + tid], enc_f32(m));  // device-scope
  }
}

// ---------------------------------------------------------------------------
// Kernel 3: single block (1024 thr) — decode row-mins, loss, mean, store.
// Separate launch: kernel-boundary coherence makes plain loads correct
// (verified R0-R2); per-block device fences inside simmin cost ~340us (R3/R4).
// ---------------------------------------------------------------------------
__global__ __launch_bounds__(1024) void finalize_kernel(
    const uint32_t* __restrict__ minenc, const float* __restrict__ cos_ap,
    float* __restrict__ out)
{
  float sum = 0.0f;
#pragma unroll
  for (int r = threadIdx.x; r < B_ROWS; r += 1024)
    sum += fmaxf(0.0f, 1.0f + cos_ap[r] - dec_f32(minenc[r]));

#pragma unroll
  for (int d = 1; d < 64; d <<= 1) sum += __shfl_xor(sum, d);
  __shared__ float s[16];
  if ((threadIdx.x & 63) == 0) s[threadIdx.x >> 6] = sum;
  __syncthreads();
  if (threadIdx.x < 64) {
    float t = (threadIdx.x < 16) ? s[threadIdx.x] : 0.0f;
#pragma unroll
    for (int d = 1; d < 16; d <<= 1) t += __shfl_xor(t, d);
    if (threadIdx.x == 0) out[0] = t * (1.0f / (float)B_ROWS);
  }
}

// ---------------------------------------------------------------------------
extern "C" void kernel_launch(void* const* d_in, const int* in_sizes, int n_in,
                              void* d_out, int out_size, void* d_ws, size_t ws_size,
                              hipStream_t stream) {
  const float* anchor   = (const float*)d_in[0];
  const float* positive = (const float*)d_in[1];

  char* ws = (char*)d_ws;
  uint32_t* a8     = (uint32_t*)(ws);                                // 4 MB
  uint32_t* p8     = (uint32_t*)(ws + (4ull << 20));                 // 4 MB
  float*    cos_ap = (float*)(ws + (8ull << 20));                    // 32 KB
  uint32_t* minenc = (uint32_t*)(ws + (8ull << 20) + (32ull << 10)); // 32 KB
  float*    out = (float*)d_out;

  norm_kernel<<<B_ROWS / 4, 256, 0, stream>>>(anchor, positive, a8, p8,
                                              cos_ap, minenc);
  simmin_kernel<<<N_BLOCKS, 512, 0, stream>>>((const uint8_t*)a8,
                                              (const uint8_t*)p8, minenc);
  finalize_kernel<<<1, 1024, 0, stream>>>(minenc, cos_ap, out);
}

// Round 7
// 125.172 us; speedup vs baseline: 3.8772x; 1.0054x over previous
//
#include <hip/hip_runtime.h>
#include <stdint.h>

typedef int   i32x8 __attribute__((ext_vector_type(8)));
typedef float f32x4 __attribute__((ext_vector_type(4)));

#define B_ROWS 8192
#define D_DIM  512
#define BM 256
#define BN 256
#define BK 128
#define N_BLOCKS 1024   // (8192/256)^2

// monotone float<->uint encoding: enc order == float order (so uint atomicMin
// == float min). f>=0: set sign bit; f<0: bitwise NOT.
__device__ __forceinline__ uint32_t enc_f32(float f) {
  uint32_t s = __float_as_uint(f);
  return (s & 0x80000000u) ? ~s : (s | 0x80000000u);
}
__device__ __forceinline__ float dec_f32(uint32_t e) {
  uint32_t s = (e & 0x80000000u) ? (e ^ 0x80000000u) : ~e;
  return __uint_as_float(s);
}

// ---------------------------------------------------------------------------
// Kernel 1: per-row normalize (fp32 -> fp8 e4m3) + cos(anchor, positive).
// Wave per row. Also inits minenc[r] = +inf encoding (replaces a memset node).
// ---------------------------------------------------------------------------
__global__ __launch_bounds__(256) void norm_kernel(
    const float* __restrict__ anchor, const float* __restrict__ positive,
    uint32_t* __restrict__ a8, uint32_t* __restrict__ p8,
    float* __restrict__ cos_ap, uint32_t* __restrict__ minenc)
{
  const int wave = threadIdx.x >> 6, lane = threadIdx.x & 63;
  const int r = blockIdx.x * 4 + wave;

  const float4* av = (const float4*)(anchor   + (size_t)r * D_DIM) + lane * 2;
  const float4* pv = (const float4*)(positive + (size_t)r * D_DIM) + lane * 2;
  float4 a0 = av[0], a1 = av[1];
  float4 p0 = pv[0], p1 = pv[1];

  float sa = a0.x*a0.x + a0.y*a0.y + a0.z*a0.z + a0.w*a0.w
           + a1.x*a1.x + a1.y*a1.y + a1.z*a1.z + a1.w*a1.w;
  float sp = p0.x*p0.x + p0.y*p0.y + p0.z*p0.z + p0.w*p0.w
           + p1.x*p1.x + p1.y*p1.y + p1.z*p1.z + p1.w*p1.w;
  float dp = a0.x*p0.x + a0.y*p0.y + a0.z*p0.z + a0.w*p0.w
           + a1.x*p1.x + a1.y*p1.y + a1.z*p1.z + a1.w*p1.w;

#pragma unroll
  for (int d = 1; d < 64; d <<= 1) {
    sa += __shfl_xor(sa, d);
    sp += __shfl_xor(sp, d);
    dp += __shfl_xor(dp, d);
  }

  const float na = sqrtf(sa), np = sqrtf(sp);
  const float ia = 1.0f / na, ip = 1.0f / np;

  float na0 = a0.x*ia, na1 = a0.y*ia, na2 = a0.z*ia, na3 = a0.w*ia;
  float na4 = a1.x*ia, na5 = a1.y*ia, na6 = a1.z*ia, na7 = a1.w*ia;
  float np0 = p0.x*ip, np1 = p0.y*ip, np2 = p0.z*ip, np3 = p0.w*ip;
  float np4 = p1.x*ip, np5 = p1.y*ip, np6 = p1.z*ip, np7 = p1.w*ip;

  uint32_t aw0 = __builtin_amdgcn_cvt_pk_fp8_f32(na0, na1, 0,  false);
  aw0          = __builtin_amdgcn_cvt_pk_fp8_f32(na2, na3, aw0, true);
  uint32_t aw1 = __builtin_amdgcn_cvt_pk_fp8_f32(na4, na5, 0,  false);
  aw1          = __builtin_amdgcn_cvt_pk_fp8_f32(na6, na7, aw1, true);
  uint32_t pw0 = __builtin_amdgcn_cvt_pk_fp8_f32(np0, np1, 0,  false);
  pw0          = __builtin_amdgcn_cvt_pk_fp8_f32(np2, np3, pw0, true);
  uint32_t pw1 = __builtin_amdgcn_cvt_pk_fp8_f32(np4, np5, 0,  false);
  pw1          = __builtin_amdgcn_cvt_pk_fp8_f32(np6, np7, pw1, true);

  ((uint2*)a8)[(size_t)r * 64 + lane] = make_uint2(aw0, aw1);
  ((uint2*)p8)[(size_t)r * 64 + lane] = make_uint2(pw0, pw1);

  if (lane == 0) {
    cos_ap[r] = dp / fmaxf(na * np, 1e-8f);
    minenc[r] = 0xFFFFFFFFu;   // +inf in monotone encoding
  }
}

// ---------------------------------------------------------------------------
// global -> LDS direct load, 16B per lane (dest = wave-uniform base + lane*16).
// ---------------------------------------------------------------------------
__device__ __forceinline__ void load16_to_lds(const void* g, void* l) {
  __builtin_amdgcn_global_load_lds(
      (__attribute__((address_space(1))) uint32_t*)(uintptr_t)(g),
      (__attribute__((address_space(3))) uint32_t*)(uintptr_t)(l),
      16, 0, 0);
}

// ---------------------------------------------------------------------------
// Kernel 2: 256x256 fp8 MX-MFMA tile of sim = A_n * P_n^T (scale=1.0), fused
// diagonal-masked row-min -> device atomicMin on encoded floats.
//
// R7: 8-phase-style schedule (T3+T4+T5 port). R6's 2-barrier/K-iter structure
// capped MfmaUtil at 22% (m233: 2-phase critical path = stage+vmcnt(0)+bar
// ~72% overhead, tile-size-independent). Restructure: 4 phases per K-tile,
// each phase = {ds_read 2 A-frags (ph0 also 4 B-frags) | stage issue ->
// s_barrier -> lgkmcnt(0) -> setprio(1) -> 8 MFMA -> setprio(0) -> s_barrier}.
// Counted vmcnt: prologue stages t0+t1 (vmcnt(8) leaves t1 in flight); t2
// staged during tile1 ph0/ph1, t3 during tile2 -> stage loads get >=2 phases
// of MFMA cover; tile-boundary vmcnt(0) finds them complete (never a cold
// drain). Raw s_barrier (no implicit vmcnt0); "memory"-clobbered waitcnt asm
// pins ordering; sched_barrier(0) after lgkmcnt (guide rule #18).
// WAR safety: stage for tile t+2 (same buf parity) issues only after tile t's
// closing barrier.
//   Settled: A must be LDS-staged (R2/R4/R5: A-from-global = 512B-stride
//   gather, 4x MFMA time); no device fences inside simmin (R3/R4: -340us).
// Fragment/swizzle/epilogue math byte-identical to verified R6.
//
// Block swizzle: xcd = bid&7 owns A-rowTiles [xcd*4, xcd*4+4) for ALL 32
// colTiles (A slice 512 KB/XCD stays L2-resident; P streams 4 MB/XCD).
// ---------------------------------------------------------------------------
__global__ __launch_bounds__(512, 2) void simmin_kernel(
    const uint8_t* __restrict__ a8, const uint8_t* __restrict__ p8,
    uint32_t* __restrict__ minenc)
{
  __shared__ __attribute__((aligned(16))) uint8_t Alds[2][BM * BK];
  __shared__ __attribute__((aligned(16))) uint8_t Plds[2][BN * BK];
  __shared__ float redmin[2][4][128];

  const int tid  = threadIdx.x;
  const int lane = tid & 63;
  const int wave = tid >> 6;          // 0..7
  const int waveM = wave >> 2;        // 0..1 (row half)
  const int waveN = wave & 3;         // 0..3 (col quarter)
  const int quad = lane >> 4;
  const int l15  = lane & 15;

  // super-tile swizzle (see header comment): bijective over 1024 blocks
  const int bid = blockIdx.x;
  const int blockRow = (bid & 7) * 4 + ((bid >> 3) & 3);  // 0..31
  const int blockCol = bid >> 5;                          // 0..31

  f32x4 acc[8][4];
  const f32x4 zero = {0.f, 0.f, 0.f, 0.f};
#pragma unroll
  for (int i = 0; i < 8; i++)
#pragma unroll
    for (int j = 0; j < 4; j++) acc[i][j] = zero;

  // staging: chunk = 8 rows x 128B; lane i: row = i/8, XOR-swizzled k-slot
  // fetched pre-swizzled on the global side (LDS side must stay contiguous).
  const int srow = lane >> 3;
  const int sk   = (lane & 7) ^ srow;
  const uint8_t* aBase = a8 + (size_t)(blockRow * BM) * D_DIM;
  const uint8_t* pBase = p8 + (size_t)(blockCol * BN) * D_DIM;

  // stage one half-tile (128 rows of A and P) of K-tile t into buf.
  // 16 chunks of 8 rows; each thread: 2 chunks x 2 arrays = 4 loads.
  auto stage_half = [&](int t, int h, int buf) {
#pragma unroll
    for (int c = 0; c < 2; c++) {
      const int chunk = h * 16 + wave * 2 + c;   // h*16 .. h*16+15
      const size_t goff = (size_t)(chunk * 8 + srow) * D_DIM + t * BK + sk * 16;
      load16_to_lds(aBase + goff, &Alds[buf][chunk * 1024]);
      load16_to_lds(pBase + goff, &Plds[buf][chunk * 1024]);
    }
  };

  auto read_af = [&](int buf, int mf) -> i32x8 {
    const int r = waveM * 128 + mf * 16 + l15;
    const int rx = r & 7;
    const int4 lo = *(const int4*)&Alds[buf][r * BK + (((quad * 2 + 0) ^ rx) * 16)];
    const int4 hi = *(const int4*)&Alds[buf][r * BK + (((quad * 2 + 1) ^ rx) * 16)];
    return (i32x8){lo.x, lo.y, lo.z, lo.w, hi.x, hi.y, hi.z, hi.w};
  };
  auto read_bf = [&](int buf, int nf) -> i32x8 {
    const int r = waveN * 64 + nf * 16 + l15;
    const int rx = r & 7;
    const int4 lo = *(const int4*)&Plds[buf][r * BK + (((quad * 2 + 0) ^ rx) * 16)];
    const int4 hi = *(const int4*)&Plds[buf][r * BK + (((quad * 2 + 1) ^ rx) * 16)];
    return (i32x8){lo.x, lo.y, lo.z, lo.w, hi.x, hi.y, hi.z, hi.w};
  };

#define MFMA_ROW(mf_, af_)                                                    \
  _Pragma("unroll")                                                           \
  for (int nf = 0; nf < 4; nf++)                                              \
    acc[mf_][nf] = __builtin_amdgcn_mfma_scale_f32_16x16x128_f8f6f4(          \
        af_, bfr[nf], acc[mf_][nf], 0, 0, 0, 0x7F7F7F7F, 0, 0x7F7F7F7F);

  // phase = {ds_read 2 A-frags | stage issue -> bar -> lgkm0 -> prio1 ->
  //          8 MFMA -> prio0 -> tail(vmcnt) -> bar}
#define PHASE(mfA, mfB, STAGE_STMT, TAIL_STMT)                                \
  {                                                                           \
    i32x8 afa = read_af(buf, (mfA));                                          \
    i32x8 afb = read_af(buf, (mfB));                                          \
    STAGE_STMT;                                                               \
    __builtin_amdgcn_s_barrier();                                             \
    asm volatile("s_waitcnt lgkmcnt(0)" ::: "memory");                        \
    __builtin_amdgcn_sched_barrier(0);                                        \
    __builtin_amdgcn_s_setprio(1);                                            \
    MFMA_ROW((mfA), afa);                                                     \
    MFMA_ROW((mfB), afb);                                                     \
    __builtin_amdgcn_s_setprio(0);                                            \
    TAIL_STMT;                                                                \
    __builtin_amdgcn_s_barrier();                                             \
  }

  // prologue: stage K-tiles 0 and 1 (16 loads/thread); wait own t0 loads
  // (vmcnt(8) leaves t1's 8 in flight); barrier -> everyone's t0 complete.
  stage_half(0, 0, 0); stage_half(0, 1, 0);
  stage_half(1, 0, 1); stage_half(1, 1, 1);
  asm volatile("s_waitcnt vmcnt(8)" ::: "memory");
  __builtin_amdgcn_s_barrier();

#pragma unroll
  for (int t = 0; t < 4; t++) {
    const int buf = t & 1;

    i32x8 bfr[4];   // B fragments: read once per tile, live across 4 phases
#pragma unroll
    for (int nf = 0; nf < 4; nf++) bfr[nf] = read_bf(buf, nf);

    PHASE(0, 1,
          { if (t == 1) stage_half(2, 0, 0);  if (t == 2) stage_half(3, 0, 1); },
          {});
    PHASE(2, 3,
          { if (t == 1) stage_half(2, 1, 0);  if (t == 2) stage_half(3, 1, 1); },
          {});
    PHASE(4, 5, {}, {});
    PHASE(6, 7, {},
          { if (t < 3) asm volatile("s_waitcnt vmcnt(0)" ::: "memory"); });
  }
#undef PHASE
#undef MFMA_ROW

  // ---- fused epilogue: per-row min over this block's 256 cols, diag masked
  const int rowTileBase = blockRow * BM + waveM * 128;
  const int colTileBase = blockCol * BN + waveN * 64;

  float rm[8][4];
#pragma unroll
  for (int mf = 0; mf < 8; mf++)
#pragma unroll
    for (int r = 0; r < 4; r++) rm[mf][r] = 3.0e38f;

#pragma unroll
  for (int mf = 0; mf < 8; mf++) {
#pragma unroll
    for (int nf = 0; nf < 4; nf++) {
      const int col = colTileBase + nf * 16 + l15;
#pragma unroll
      for (int r = 0; r < 4; r++) {
        const int row = rowTileBase + mf * 16 + quad * 4 + r;
        const float v = acc[mf][nf][r];
        rm[mf][r] = (row == col) ? rm[mf][r] : fminf(rm[mf][r], v);
      }
    }
  }
  // fold across the 16 lanes of each l15-group (cols congruent mod 16)
#pragma unroll
  for (int d = 1; d < 16; d <<= 1)
#pragma unroll
    for (int mf = 0; mf < 8; mf++)
#pragma unroll
      for (int r = 0; r < 4; r++)
        rm[mf][r] = fminf(rm[mf][r], __shfl_xor(rm[mf][r], d));

  // each wave: 128 row-mins over its 64 cols -> LDS slice [waveM][waveN]
  if (l15 == 0) {
#pragma unroll
    for (int mf = 0; mf < 8; mf++)
#pragma unroll
      for (int r = 0; r < 4; r++)
        redmin[waveM][waveN][mf * 16 + quad * 4 + r] = rm[mf][r];
  }
  __syncthreads();

  // fold 4 waveN slices; tid = waveM_r*128 + local row
  if (tid < 256) {
    const int wm = tid >> 7, idx = tid & 127;
    const float m = fminf(fminf(redmin[wm][0][idx], redmin[wm][1][idx]),
                          fminf(redmin[wm][2][idx], redmin[wm][3][idx]));
    atomicMin(&minenc[blockRow * BM + tid], enc_f32(m));  // device-scope
  }
}

// ---------------------------------------------------------------------------
// Kernel 3: single block (1024 thr) — decode row-mins, loss, mean, store.
// Separate launch: kernel-boundary coherence makes plain loads correct
// (verified R0-R2); per-block device fences inside simmin cost ~340us (R3/R4).
// ---------------------------------------------------------------------------
__global__ __launch_bounds__(1024) void finalize_kernel(
    const uint32_t* __restrict__ minenc, const float* __restrict__ cos_ap,
    float* __restrict__ out)
{
  float sum = 0.0f;
#pragma unroll
  for (int r = threadIdx.x; r < B_ROWS; r += 1024)
    sum += fmaxf(0.0f, 1.0f + cos_ap[r] - dec_f32(minenc[r]));

#pragma unroll
  for (int d = 1; d < 64; d <<= 1) sum += __shfl_xor(sum, d);
  __shared__ float s[16];
  if ((threadIdx.x & 63) == 0) s[threadIdx.x >> 6] = sum;
  __syncthreads();
  if (threadIdx.x < 64) {
    float t = (threadIdx.x < 16) ? s[threadIdx.x] : 0.0f;
#pragma unroll
    for (int d = 1; d < 16; d <<= 1) t += __shfl_xor(t, d);
    if (threadIdx.x == 0) out[0] = t * (1.0f / (float)B_ROWS);
  }
}

// ---------------------------------------------------------------------------
extern "C" void kernel_launch(void* const* d_in, const int* in_sizes, int n_in,
                              void* d_out, int out_size, void* d_ws, size_t ws_size,
                              hipStream_t stream) {
  const float* anchor   = (const float*)d_in[0];
  const float* positive = (const float*)d_in[1];

  char* ws = (char*)d_ws;
  uint32_t* a8     = (uint32_t*)(ws);                                // 4 MB
  uint32_t* p8     = (uint32_t*)(ws + (4ull << 20));                 // 4 MB
  float*    cos_ap = (float*)(ws + (8ull << 20));                    // 32 KB
  uint32_t* minenc = (uint32_t*)(ws + (8ull << 20) + (32ull << 10)); // 32 KB
  float*    out = (float*)d_out;

  norm_kernel<<<B_ROWS / 4, 256, 0, stream>>>(anchor, positive, a8, p8,
                                              cos_ap, minenc);
  simmin_kernel<<<N_BLOCKS, 512, 0, stream>>>((const uint8_t*)a8,
                                              (const uint8_t*)p8, minenc);
  finalize_kernel<<<1, 1024, 0, stream>>>(minenc, cos_ap, out);
}